// Round 18
// baseline (510.794 us; speedup 1.0000x reference)
//
#include <hip/hip_runtime.h>

#define T_TOKENS 4096
#define HDIM 1024

typedef __attribute__((ext_vector_type(8))) short bf16x8;
typedef __attribute__((ext_vector_type(4))) float f32x4;

#define EXP2F(x) __builtin_amdgcn_exp2f(x)

static __device__ inline unsigned short f2bf(float f) {
  unsigned u = __float_as_uint(f);
  unsigned r = (u + 0x7FFFu + ((u >> 16) & 1u)) >> 16;
  return (unsigned short)r;
}
static __device__ __forceinline__ unsigned cvtpk(float lo, float hi) {
  unsigned r;
  asm("v_cvt_pk_bf16_f32 %0, %1, %2" : "=v"(r) : "v"(lo), "v"(hi));
  return r;
}
static __device__ __forceinline__ void gl16(const void* g, void* l) {
  __builtin_amdgcn_global_load_lds((const __attribute__((address_space(1))) void*)g,
                                   (__attribute__((address_space(3))) void*)l, 16, 0, 0);
}

// ---------------------------------------------------------------- LayerNorm (fp32 in, bf16 out)
__launch_bounds__(256)
__global__ void ln_kernel(const float* __restrict__ in, const float* __restrict__ g,
                          const float* __restrict__ b, unsigned short* __restrict__ out) {
  const int row = blockIdx.x;
  const int tid = threadIdx.x;
  const long base = (long)row * HDIM;
  float4 v = *(const float4*)(in + base + tid * 4);
  __shared__ float red[256];
  red[tid] = v.x + v.y + v.z + v.w;
  __syncthreads();
  for (int st = 128; st > 0; st >>= 1) {
    if (tid < st) red[tid] += red[tid + st];
    __syncthreads();
  }
  const float mean = red[0] * (1.f / HDIM);
  __syncthreads();
  const float dx = v.x - mean, dy = v.y - mean, dz = v.z - mean, dw = v.w - mean;
  red[tid] = dx * dx + dy * dy + dz * dz + dw * dw;
  __syncthreads();
  for (int st = 128; st > 0; st >>= 1) {
    if (tid < st) red[tid] += red[tid + st];
    __syncthreads();
  }
  const float rstd = rsqrtf(red[0] * (1.f / HDIM) + 1e-6f);
  const int c = tid * 4;
  const float4 g4 = *(const float4*)(g + c);
  const float4 b4 = *(const float4*)(b + c);
  uint2 o;
  o.x = cvtpk(dx * rstd * g4.x + b4.x, dy * rstd * g4.y + b4.y);
  o.y = cvtpk(dz * rstd * g4.z + b4.z, dw * rstd * g4.w + b4.w);
  *(uint2*)(out + base + c) = o;
}

// ------------------------------------------------------------ expert groups
__launch_bounds__(256)
__global__ void build_groups(const int* __restrict__ pids, const int* __restrict__ mids,
                             int* __restrict__ gen_cnt, int* __restrict__ gen_list,
                             int* __restrict__ mod_cnt, int* __restrict__ mod_list) {
  const int t = blockIdx.x * 256 + threadIdx.x;
  if (t >= T_TOKENS) return;
  const int p = pids[t];
  const int ge = p & 7;
  int s = atomicAdd(&gen_cnt[ge], 1);
  if (s < 512) gen_list[ge * 512 + s] = t;
  const int g = mids[t] * 4 + (p & 3);
  s = atomicAdd(&mod_cnt[g], 1);
  if (s < 1024) mod_list[g * 1024 + s] = t;
}

// ------------------------------------------- weight transpose+convert: W[K][N] fp32 -> Wt[N][K] bf16
__launch_bounds__(256)
__global__ void convert_w(const float* __restrict__ W, unsigned short* __restrict__ Wt,
                          int K, int N) {
  const long zo = (long)blockIdx.z * K * N;
  const float* Wp = W + zo;
  unsigned short* Wo = Wt + zo;
  const int n0 = blockIdx.x * 64, k0 = blockIdx.y * 64;
  __shared__ float T[64][65];
  const int tid = threadIdx.x;
#pragma unroll
  for (int i = 0; i < 4; ++i) {
    const int item = tid + i * 256;
    const int kk = item >> 4, c4 = (item & 15) * 4;
    const float4 v = *(const float4*)(Wp + (long)(k0 + kk) * N + n0 + c4);
    T[c4 + 0][kk] = v.x; T[c4 + 1][kk] = v.y; T[c4 + 2][kk] = v.z; T[c4 + 3][kk] = v.w;
  }
  __syncthreads();
#pragma unroll
  for (int i = 0; i < 4; ++i) {
    const int item = tid + i * 256;
    const int nn = item >> 4, k4 = (item & 15) * 4;
    uint2 p;
    p.x = cvtpk(T[nn][k4 + 0], T[nn][k4 + 1]);
    p.y = cvtpk(T[nn][k4 + 2], T[nn][k4 + 3]);
    *(uint2*)(Wo + (long)(n0 + nn) * K + k0 + k4) = p;
  }
}

// --------------------------------------------------- bf16 MFMA tiled GEMM
// Tile BM x BN, BK=64, 4 waves. Double-buffered K-loop.
// fp32-W path: float4 loads -> regs -> raw LDS -> transpose+cvt -> Bs.
enum { MODE_DENSE = 0, MODE_GEN = 1, MODE_MOD = 2 };
enum { OM_F32R = 0, OM_BF16 = 1, OM_QKV = 2 };

template <int MODE, int OMODE, bool WBF16, bool BIAS, int BM, int BN>
__launch_bounds__(256)
__global__ void mgemm(const unsigned short* __restrict__ A,
                      const void* __restrict__ w0, const float* __restrict__ w1,
                      const float* __restrict__ w2, const float* __restrict__ w3,
                      long wstep, const float* __restrict__ bias,
                      const float* __restrict__ resid, void* __restrict__ Cout,
                      unsigned short* __restrict__ qb, unsigned short* __restrict__ kb,
                      unsigned short* __restrict__ vtb,
                      int K, int N,
                      const int* __restrict__ cnts, const int* __restrict__ rowlist,
                      int cap) {
  const int z = blockIdx.z;
  const int n0 = blockIdx.x * BN;
  const int m0 = blockIdx.y * BM;

  int Meff = 1 << 30;
  const int* list = nullptr;
  if constexpr (MODE != MODE_DENSE) {
    Meff = cnts[z];
    if (m0 >= Meff) return;
    list = rowlist + z * cap;
  }

  constexpr int MR = BM / 32;
  constexpr int NR = BN / 32;
  constexpr int JB = BN / 32;            // transpose items per thread
  constexpr int RAWP = (BN * 64) / 1024; // float4 raw-load passes (BN=64 -> 4)
  constexpr int ABUF = BM * 128;
  constexpr int BBUF = BN * 128;
  __shared__ char As[2 * ABUF];
  __shared__ char Bs[2 * BBUF];
  __shared__ char Braw[WBF16 ? 16 : 64 * 272];  // [64 k][68 dwords] fp32

  const int tid = threadIdx.x;
  const int w = tid >> 6;
  const int lane = tid & 63;
  const int wm = w >> 1, wn = w & 1;
  const int srow = lane >> 3, sc = lane & 7;

  const unsigned short* asrc[MR];
#pragma unroll
  for (int i = 0; i < MR; ++i) {
    const int r = w * (BM / 4) + i * 8 + srow;
    long tok;
    if constexpr (MODE == MODE_DENSE) {
      tok = m0 + r;
    } else {
      int gm = m0 + r;
      if (gm >= Meff) gm = Meff - 1;
      tok = (long)list[gm];
    }
    asrc[i] = A + tok * (long)K + (sc ^ (r & 7)) * 8;
  }

  const unsigned short* bsrc[NR];
  const float* wcol = nullptr;   // fp32 path: W + n0
  int rk[4], rn[4];
  if constexpr (WBF16) {
    const unsigned short* W = (const unsigned short*)w0;
    if constexpr (MODE != MODE_DENSE) W += (long)z * wstep;
#pragma unroll
    for (int i = 0; i < NR; ++i) {
      const int r = w * (BN / 4) + i * 8 + srow;
      bsrc[i] = W + (long)(n0 + r) * K + (sc ^ (r & 7)) * 8;
    }
  } else {
    const float* W;
    if constexpr (MODE == MODE_MOD) {
      const int mm = z >> 2;
      const float* basep = (mm == 0) ? (const float*)w0 : (mm == 1) ? w1 : (mm == 2) ? w2 : w3;
      W = basep + (long)(z & 3) * wstep;
    } else {
      W = (const float*)w0 + (MODE != MODE_DENSE ? (long)z * wstep : 0);
    }
    wcol = W + n0;
#pragma unroll
    for (int p = 0; p < RAWP; ++p) {
      const int item = tid + p * 256;
      rk[p] = item >> (BN == 64 ? 4 : 5);       // item / (BN/4)
      rn[p] = (item & (BN / 4 - 1)) * 4;
    }
  }

  f32x4 acc[MR][NR] = {};
  float4 braw[RAWP];

  auto stageA = [&](int s, int kt) {
#pragma unroll
    for (int i = 0; i < MR; ++i)
      gl16(asrc[i] + kt, As + s * ABUF + w * (BM * 32) + i * 1024);
  };
  auto stageB16 = [&](int s, int kt) {
#pragma unroll
    for (int i = 0; i < NR; ++i)
      gl16(bsrc[i] + kt, Bs + s * BBUF + w * (BN * 32) + i * 1024);
  };
  auto loadRaw = [&](int kt) {
#pragma unroll
    for (int p = 0; p < RAWP; ++p)
      braw[p] = *(const float4*)(wcol + (long)(kt + rk[p]) * N + rn[p]);
  };
  auto writeRaw = [&]() {
#pragma unroll
    for (int p = 0; p < RAWP; ++p)
      *(float4*)(Braw + rk[p] * 272 + rn[p] * 4) = braw[p];
  };
  auto transposeB = [&](int s) {
#pragma unroll
    for (int j = 0; j < JB; ++j) {
      const int item = tid + j * 256;
      const int kc = item / BN;        // 0..7
      const int nl = item % BN;
      float v[8];
#pragma unroll
      for (int u = 0; u < 8; ++u)
        v[u] = *(const float*)(Braw + (kc * 8 + u) * 272 + nl * 4);
      uint4 p;
      p.x = cvtpk(v[0], v[1]);
      p.y = cvtpk(v[2], v[3]);
      p.z = cvtpk(v[4], v[5]);
      p.w = cvtpk(v[6], v[7]);
      *(uint4*)(Bs + s * BBUF + ((nl * 128 + kc * 16) ^ ((nl & 7) << 4))) = p;
    }
  };
  auto compute = [&](int s) {
#pragma unroll
    for (int kk = 0; kk < 2; ++kk) {
      const int kb2 = kk * 64 + (lane >> 4) * 16;
      bf16x8 af[MR], bfr[NR];
#pragma unroll
      for (int f = 0; f < MR; ++f) {
        const int ar = wm * (BM / 2) + f * 16 + (lane & 15);
        af[f] = *(bf16x8*)(As + s * ABUF + ((ar * 128 + kb2) ^ ((ar & 7) << 4)));
      }
#pragma unroll
      for (int f = 0; f < NR; ++f) {
        const int br = wn * (BN / 2) + f * 16 + (lane & 15);
        bfr[f] = *(bf16x8*)(Bs + s * BBUF + ((br * 128 + kb2) ^ ((br & 7) << 4)));
      }
#pragma unroll
      for (int mf = 0; mf < MR; ++mf)
#pragma unroll
        for (int nf = 0; nf < NR; ++nf)
          acc[mf][nf] =
              __builtin_amdgcn_mfma_f32_16x16x32_bf16(af[mf], bfr[nf], acc[mf][nf], 0, 0, 0);
    }
  };

  const int nk = K >> 6;
  int sel = 0;
  if constexpr (WBF16) {
    stageA(0, 0);
    stageB16(0, 0);
    __syncthreads();
    for (int t = 0; t < nk; ++t) {
      const bool more = (t + 1) < nk;
      const int ktn = (t + 1) * 64;
      if (more) {
        stageA(sel ^ 1, ktn);
        stageB16(sel ^ 1, ktn);
      }
      compute(sel);
      __syncthreads();
      sel ^= 1;
    }
  } else {
    stageA(0, 0);
    loadRaw(0);
    writeRaw();
    __syncthreads();
    transposeB(0);
    __syncthreads();
    for (int t = 0; t < nk; ++t) {
      const bool more = (t + 1) < nk;
      const int ktn = (t + 1) * 64;
      if (more) {
        stageA(sel ^ 1, ktn);
        loadRaw(ktn);
      }
      compute(sel);
      if (more) writeRaw();
      __syncthreads();
      if (more) transposeB(sel ^ 1);
      __syncthreads();
      sel ^= 1;
    }
  }

  // ---- epilogue (C/D layout: col=lane&15, row=(lane>>4)*4+r)
  const int lr4 = (lane >> 4) * 4;
  const int lc = lane & 15;
#pragma unroll
  for (int mf = 0; mf < MR; ++mf) {
#pragma unroll
    for (int r = 0; r < 4; ++r) {
      const int gm = m0 + wm * (BM / 2) + mf * 16 + lr4 + r;
      long orow;
      if constexpr (MODE == MODE_DENSE) {
        orow = gm;
      } else {
        if (gm >= Meff) continue;
        orow = (long)list[gm];
      }
#pragma unroll
      for (int nf = 0; nf < NR; ++nf) {
        const int gc = n0 + wn * (BN / 2) + nf * 16 + lc;
        float val = acc[mf][nf][r];
        if constexpr (BIAS) val += bias[gc];
        if constexpr (OMODE == OM_F32R) {
          val += resid[orow * (long)N + gc];
          ((float*)Cout)[orow * (long)N + gc] = val;
        } else if constexpr (OMODE == OM_BF16) {
          ((unsigned short*)Cout)[orow * (long)N + gc] = f2bf(val);
        } else {  // OM_QKV
          const int bb = (int)(orow >> 11), tl = (int)orow & 2047;
          const int seg = gc >> 10, hc = gc & 1023, h = hc >> 6, d = hc & 63;
          if (seg == 0)
            qb[(((long)(bb * 16 + h) * 2048) + tl) * 64 + d] = f2bf(val * 0.18033688011112042f);
          else if (seg == 1)
            kb[(((long)(bb * 16 + h) * 2048) + tl) * 64 + d] = f2bf(val);
          else
            vtb[((long)(bb * 16 + h) * 64 + d) * 2048 + tl] = f2bf(val);
        }
      }
    }
  }
}

// ----------------------------------------------------------- MFMA attention
// QBLK=128: each wave owns 32 q-rows (two halves sharing K/V frags).
__launch_bounds__(256)
__global__ void attn_kernel(const unsigned short* __restrict__ Qb,
                            const unsigned short* __restrict__ Kb,
                            const unsigned short* __restrict__ Vtb,
                            unsigned short* __restrict__ out) {
  const int lin = blockIdx.x + blockIdx.y * 16;   // 0..511
  const int xcd = lin & 7, rank = lin >> 3;       // 0..63
  const int bh = xcd * 4 + (rank >> 4);
  const int qt = rank & 15;
  const int b = bh >> 4, h = bh & 15;
  const int tid = threadIdx.x;
  const int w = tid >> 6;
  const int lane = tid & 63;
  const int g = lane >> 4;
  const int q = lane & 15;

  __shared__ char Ksb[128 * 128];
  __shared__ char Vsb[64 * 256];
  __shared__ char Psb[4 * 32 * 256];
  char* Pwb = Psb + w * 32 * 256;
  const int qx = q << 4;

  const unsigned short* Qh = Qb + ((long)(b * 16 + h) * 2048 + qt * 128) * 64;
  const unsigned short* Kh = Kb + (long)(b * 16 + h) * 2048 * 64;
  const unsigned short* Vh = Vtb + (long)(b * 16 + h) * 64 * 2048;

  bf16x8 qfA[2], qfB[2];
#pragma unroll
  for (int kst = 0; kst < 2; ++kst) {
    qfA[kst] = *(const bf16x8*)(Qh + (w * 32 + q) * 64 + kst * 32 + g * 8);
    qfB[kst] = *(const bf16x8*)(Qh + (w * 32 + 16 + q) * 64 + kst * 32 + g * 8);
  }

  const unsigned short* ksrc[4];
  const unsigned short* vsrc[4];
  char* kld = Ksb + w * 4096;
  char* vld = Vsb + w * 4096;
#pragma unroll
  for (int i = 0; i < 4; ++i) {
    const int r = w * 32 + i * 8 + (lane >> 3);
    ksrc[i] = Kh + (long)r * 64 + ((lane & 7) ^ (r & 7)) * 8;
    const int d = w * 16 + i * 4 + (lane >> 4);
    vsrc[i] = Vh + (long)d * 2048 + ((lane & 15) ^ (d & 7)) * 8;
  }

  float mA = -1e30f, lA = 0.f, mB = -1e30f, lB = 0.f;
  f32x4 accA[4] = {}, accB[4] = {};

  for (int kt = 0; kt < 16; ++kt) {
    __syncthreads();
#pragma unroll
    for (int i = 0; i < 4; ++i) gl16(ksrc[i] + (long)kt * 128 * 64, kld + i * 1024);
#pragma unroll
    for (int i = 0; i < 4; ++i) gl16(vsrc[i] + kt * 128, vld + i * 1024);
    __syncthreads();

    f32x4 sfA[8], sfB[8];
#pragma unroll
    for (int f = 0; f < 8; ++f) {
      const int krow = f * 16 + q;
      const int sw = (krow & 7) << 4;
      const bf16x8 k0 = *(bf16x8*)(Ksb + krow * 128 + ((g * 16) ^ sw));
      const bf16x8 k1 = *(bf16x8*)(Ksb + krow * 128 + ((64 + g * 16) ^ sw));
      f32x4 tA = {};
      tA = __builtin_amdgcn_mfma_f32_16x16x32_bf16(k0, qfA[0], tA, 0, 0, 0);
      sfA[f] = __builtin_amdgcn_mfma_f32_16x16x32_bf16(k1, qfA[1], tA, 0, 0, 0);
      f32x4 tB = {};
      tB = __builtin_amdgcn_mfma_f32_16x16x32_bf16(k0, qfB[0], tB, 0, 0, 0);
      sfB[f] = __builtin_amdgcn_mfma_f32_16x16x32_bf16(k1, qfB[1], tB, 0, 0, 0);
    }

    {
      float pm = fmaxf(fmaxf(sfA[0][0], sfA[0][1]), fmaxf(sfA[0][2], sfA[0][3]));
#pragma unroll
      for (int f = 1; f < 8; ++f)
        pm = fmaxf(pm, fmaxf(fmaxf(sfA[f][0], sfA[f][1]), fmaxf(sfA[f][2], sfA[f][3])));
      pm = fmaxf(pm, __shfl_xor(pm, 16));
      pm = fmaxf(pm, __shfl_xor(pm, 32));
      float al = 1.f;
      if (!__all(pm - mA <= 8.f)) {
        const float mn = fmaxf(mA, pm);
        al = EXP2F(mA - mn);
        mA = mn;
#pragma unroll
        for (int r = 0; r < 4; ++r) {
          const float aO = __shfl(al, g * 4 + r, 64);
          accA[0][r] *= aO; accA[1][r] *= aO; accA[2][r] *= aO; accA[3][r] *= aO;
        }
      }
      float ls = 0.f;
#pragma unroll
      for (int f = 0; f < 8; ++f) {
#pragma unroll
        for (int r = 0; r < 4; ++r) sfA[f][r] = EXP2F(sfA[f][r] - mA);
        ls += (sfA[f][0] + sfA[f][1]) + (sfA[f][2] + sfA[f][3]);
      }
      ls += __shfl_xor(ls, 16);
      ls += __shfl_xor(ls, 32);
      lA = lA * al + ls;
    }
    {
      float pm = fmaxf(fmaxf(sfB[0][0], sfB[0][1]), fmaxf(sfB[0][2], sfB[0][3]));
#pragma unroll
      for (int f = 1; f < 8; ++f)
        pm = fmaxf(pm, fmaxf(fmaxf(sfB[f][0], sfB[f][1]), fmaxf(sfB[f][2], sfB[f][3])));
      pm = fmaxf(pm, __shfl_xor(pm, 16));
      pm = fmaxf(pm, __shfl_xor(pm, 32));
      float al = 1.f;
      if (!__all(pm - mB <= 8.f)) {
        const float mn = fmaxf(mB, pm);
        al = EXP2F(mB - mn);
        mB = mn;
#pragma unroll
        for (int r = 0; r < 4; ++r) {
          const float aO = __shfl(al, g * 4 + r, 64);
          accB[0][r] *= aO; accB[1][r] *= aO; accB[2][r] *= aO; accB[3][r] *= aO;
        }
      }
      float ls = 0.f;
#pragma unroll
      for (int f = 0; f < 8; ++f) {
#pragma unroll
        for (int r = 0; r < 4; ++r) sfB[f][r] = EXP2F(sfB[f][r] - mB);
        ls += (sfB[f][0] + sfB[f][1]) + (sfB[f][2] + sfB[f][3]);
      }
      ls += __shfl_xor(ls, 16);
      ls += __shfl_xor(ls, 32);
      lB = lB * al + ls;
    }

#pragma unroll
    for (int f = 0; f < 8; ++f) {
      const int col = (f * 32 + g * 8) ^ qx;
      uint2 pA; pA.x = cvtpk(sfA[f][0], sfA[f][1]); pA.y = cvtpk(sfA[f][2], sfA[f][3]);
      *(uint2*)(Pwb + q * 256 + col) = pA;
      uint2 pB; pB.x = cvtpk(sfB[f][0], sfB[f][1]); pB.y = cvtpk(sfB[f][2], sfB[f][3]);
      *(uint2*)(Pwb + (q + 16) * 256 + col) = pB;
    }

#pragma unroll
    for (int kst = 0; kst < 4; ++kst) {
      const int pcol = (kst * 64 + g * 16) ^ qx;
      const bf16x8 paA = *(bf16x8*)(Pwb + q * 256 + pcol);
      const bf16x8 paB = *(bf16x8*)(Pwb + (q + 16) * 256 + pcol);
#pragma unroll
      for (int df = 0; df < 4; ++df) {
        const int vrow = df * 16 + q;
        const int vsw = (vrow & 7) << 4;
        const bf16x8 vf = *(bf16x8*)(Vsb + vrow * 256 + ((kst * 64 + g * 16) ^ vsw));
        accA[df] = __builtin_amdgcn_mfma_f32_16x16x32_bf16(paA, vf, accA[df], 0, 0, 0);
        accB[df] = __builtin_amdgcn_mfma_f32_16x16x32_bf16(paB, vf, accB[df], 0, 0, 0);
      }
    }
  }

  float liA[4], liB[4];
#pragma unroll
  for (int r = 0; r < 4; ++r) {
    liA[r] = 1.f / __shfl(lA, g * 4 + r, 64);
    liB[r] = 1.f / __shfl(lB, g * 4 + r, 64);
  }
  unsigned short* opA = out + (long)(b * 2048 + qt * 128 + w * 32) * 1024 + h * 64;
  unsigned short* opB = opA + 16 * 1024;
#pragma unroll
  for (int df = 0; df < 4; ++df)
#pragma unroll
    for (int r = 0; r < 4; ++r) {
      const int row = g * 4 + r;
      opA[(long)row * 1024 + df * 16 + q] = f2bf(accA[df][r] * liA[r]);
      opB[(long)row * 1024 + df * 16 + q] = f2bf(accB[df][r] * liB[r]);
    }
}

// ------------------------------------------------------------------- SiLU*up (bf16)
__launch_bounds__(256)
__global__ void silu_bf(const unsigned short* __restrict__ gu, unsigned short* __restrict__ inter,
                        int IE2, int IE, int shift) {
  const int total = T_TOKENS << shift;
  for (int idx = blockIdx.x * 256 + threadIdx.x; idx < total; idx += gridDim.x * 256) {
    const int t = idx >> shift;
    const int r8 = (idx & ((1 << shift) - 1)) * 8;
    const unsigned short* gp = gu + (long)t * IE2 + r8;
    const uint4 gg = *(const uint4*)gp;
    const uint4 uu = *(const uint4*)(gp + IE);
    const unsigned gw[4] = {gg.x, gg.y, gg.z, gg.w};
    const unsigned uw[4] = {uu.x, uu.y, uu.z, uu.w};
    uint4 o;
    unsigned ow[4];
#pragma unroll
    for (int qq = 0; qq < 4; ++qq) {
      const float g0 = __uint_as_float(gw[qq] << 16);
      const float g1 = __uint_as_float(gw[qq] & 0xffff0000u);
      const float u0 = __uint_as_float(uw[qq] << 16);
      const float u1 = __uint_as_float(uw[qq] & 0xffff0000u);
      const float r0 = g0 / (1.f + __expf(-g0)) * u0;
      const float r1 = g1 / (1.f + __expf(-g1)) * u1;
      ow[qq] = cvtpk(r0, r1);
    }
    o.x = ow[0]; o.y = ow[1]; o.z = ow[2]; o.w = ow[3];
    *(uint4*)(inter + (long)t * IE + r8) = o;
  }
}

// ------------------------------------------------------------------- launch
extern "C" void kernel_launch(void* const* d_in, const int* in_sizes, int n_in,
                              void* d_out, int out_size, void* d_ws, size_t ws_size,
                              hipStream_t stream) {
  const float* x       = (const float*)d_in[0];
  const float* qkv_w   = (const float*)d_in[1];
  const float* qkv_b   = (const float*)d_in[2];
  const float* proj_w  = (const float*)d_in[3];
  const float* proj_b  = (const float*)d_in[4];
  const float* ln1_g   = (const float*)d_in[5];
  const float* ln1_b   = (const float*)d_in[6];
  const float* ln2_g   = (const float*)d_in[7];
  const float* ln2_b   = (const float*)d_in[8];
  const float* ln3_g   = (const float*)d_in[9];
  const float* ln3_b   = (const float*)d_in[10];
  const float* gen_gu  = (const float*)d_in[11];
  const float* gen_dn  = (const float*)d_in[12];
  const float* text_gu = (const float*)d_in[13];
  const float* text_dn = (const float*)d_in[14];
  const float* img_gu  = (const float*)d_in[15];
  const float* img_dn  = (const float*)d_in[16];
  const float* aud_gu  = (const float*)d_in[17];
  const float* aud_dn  = (const float*)d_in[18];
  const float* vid_gu  = (const float*)d_in[19];
  const float* vid_dn  = (const float*)d_in[20];
  const int* mids      = (const int*)d_in[21];
  const int* pids      = (const int*)d_in[22];
  float* out = (float*)d_out;
  char* ws = (char*)d_ws;

  const unsigned long MB = 1ul << 20;
  unsigned short* lnb   = (unsigned short*)(ws);            // 8 MB
  unsigned short* Qb    = (unsigned short*)(ws + 8 * MB);   // 8 MB
  unsigned short* Kb    = (unsigned short*)(ws + 16 * MB);  // 8 MB
  unsigned short* Vtb   = (unsigned short*)(ws + 24 * MB);  // 8 MB
  unsigned short* attno = (unsigned short*)(ws + 32 * MB);  // 8 MB
  unsigned short* wqkv  = (unsigned short*)(ws + 40 * MB);  // 6 MB
  unsigned short* wproj = (unsigned short*)(ws + 46 * MB);  // 2 MB
  unsigned short* wggu  = (unsigned short*)(ws + 48 * MB);  // 16 MB
  unsigned short* wgdn  = (unsigned short*)(ws + 64 * MB);  // 8 MB
  int* gen_cnt  = (int*)(ws + 72 * MB);
  int* mod_cnt  = gen_cnt + 8;
  int* gen_list = gen_cnt + 32;
  int* mod_list = gen_list + 8 * 512;
  unsigned short* guo    = Qb;   // 16 MB (Qb+Kb), reused after attention
  unsigned short* intero = Vtb;  // 8 MB, reused after attention

  (void)hipMemsetAsync(gen_cnt, 0, (8 + 16) * sizeof(int), stream);
  build_groups<<<16, 256, 0, stream>>>(pids, mids, gen_cnt, gen_list, mod_cnt, mod_list);

  convert_w<<<dim3(48, 16, 1), 256, 0, stream>>>(qkv_w, wqkv, 1024, 3072);
  convert_w<<<dim3(16, 16, 1), 256, 0, stream>>>(proj_w, wproj, 1024, 1024);
  convert_w<<<dim3(16, 16, 8), 256, 0, stream>>>(gen_gu, wggu, 1024, 1024);
  convert_w<<<dim3(16, 8, 8), 256, 0, stream>>>(gen_dn, wgdn, 512, 1024);

  // --- attention block ---
  ln_kernel<<<4096, 256, 0, stream>>>(x, ln1_g, ln1_b, lnb);
  mgemm<MODE_DENSE, OM_QKV, true, true, 128, 128><<<dim3(24, 32, 1), 256, 0, stream>>>(
      lnb, wqkv, nullptr, nullptr, nullptr, 0L, qkv_b, nullptr, nullptr,
      Qb, Kb, Vtb, 1024, 3072, nullptr, nullptr, 0);
  attn_kernel<<<dim3(16, 32, 1), 256, 0, stream>>>(Qb, Kb, Vtb, attno);
  mgemm<MODE_DENSE, OM_F32R, true, true, 128, 128><<<dim3(8, 32, 1), 256, 0, stream>>>(
      attno, wproj, nullptr, nullptr, nullptr, 0L, proj_b, x, out,
      nullptr, nullptr, nullptr, 1024, 1024, nullptr, nullptr, 0);

  // --- gen routed MLP (E=8, IE=512) ---
  ln_kernel<<<4096, 256, 0, stream>>>(out, ln2_g, ln2_b, lnb);
  mgemm<MODE_GEN, OM_BF16, true, false, 128, 128><<<dim3(8, 4, 8), 256, 0, stream>>>(
      lnb, wggu, nullptr, nullptr, nullptr, (long)1024 * 1024, nullptr, nullptr, guo,
      nullptr, nullptr, nullptr, 1024, 1024, gen_cnt, gen_list, 512);
  silu_bf<<<1024, 256, 0, stream>>>(guo, intero, 1024, 512, 6);
  mgemm<MODE_GEN, OM_F32R, true, false, 128, 128><<<dim3(8, 4, 8), 256, 0, stream>>>(
      intero, wgdn, nullptr, nullptr, nullptr, (long)1024 * 512, nullptr, out, out,
      nullptr, nullptr, nullptr, 512, 1024, gen_cnt, gen_list, 512);

  // --- modality routed MLP (fp32-W float4 + LDS-transpose path, BN=64) ---
  ln_kernel<<<4096, 256, 0, stream>>>(out, ln3_g, ln3_b, lnb);
  mgemm<MODE_MOD, OM_BF16, false, false, 128, 64><<<dim3(32, 8, 16), 256, 0, stream>>>(
      lnb, text_gu, img_gu, aud_gu, vid_gu, (long)1024 * 2048, nullptr, nullptr, guo,
      nullptr, nullptr, nullptr, 1024, 2048, mod_cnt, mod_list, 1024);
  silu_bf<<<2048, 256, 0, stream>>>(guo, intero, 2048, 1024, 7);
  mgemm<MODE_MOD, OM_F32R, false, false, 128, 64><<<dim3(16, 8, 16), 256, 0, stream>>>(
      intero, text_dn, img_dn, aud_dn, vid_dn, (long)1024 * 1024, nullptr, out, out,
      nullptr, nullptr, nullptr, 1024, 1024, mod_cnt, mod_list, 1024);
}

// Round 19
// 378.322 us; speedup vs baseline: 1.3502x; 1.3502x over previous
//
#include <hip/hip_runtime.h>

#define T_TOKENS 4096
#define HDIM 1024

typedef __attribute__((ext_vector_type(8))) short bf16x8;
typedef __attribute__((ext_vector_type(4))) float f32x4;

#define EXP2F(x) __builtin_amdgcn_exp2f(x)

static __device__ inline unsigned short f2bf(float f) {
  unsigned u = __float_as_uint(f);
  unsigned r = (u + 0x7FFFu + ((u >> 16) & 1u)) >> 16;
  return (unsigned short)r;
}
// HW packed f32->bf16 (RNE), src0 -> low16, src1 -> high16
static __device__ __forceinline__ unsigned cvtpk(float lo, float hi) {
  unsigned r;
  asm("v_cvt_pk_bf16_f32 %0, %1, %2" : "=v"(r) : "v"(lo), "v"(hi));
  return r;
}
// global -> LDS direct copy, 16B per lane; linear LDS dest, swizzle applied
// on the per-lane GLOBAL source and identically on the LDS read.
static __device__ __forceinline__ void gl16(const void* g, void* l) {
  __builtin_amdgcn_global_load_lds((const __attribute__((address_space(1))) void*)g,
                                   (__attribute__((address_space(3))) void*)l, 16, 0, 0);
}

// ---------------------------------------------------------------- LayerNorm (fp32 in, bf16 out)
__launch_bounds__(256)
__global__ void ln_kernel(const float* __restrict__ in, const float* __restrict__ g,
                          const float* __restrict__ b, unsigned short* __restrict__ out) {
  const int row = blockIdx.x;
  const int tid = threadIdx.x;
  const long base = (long)row * HDIM;
  float4 v = *(const float4*)(in + base + tid * 4);
  __shared__ float red[256];
  red[tid] = v.x + v.y + v.z + v.w;
  __syncthreads();
  for (int st = 128; st > 0; st >>= 1) {
    if (tid < st) red[tid] += red[tid + st];
    __syncthreads();
  }
  const float mean = red[0] * (1.f / HDIM);
  __syncthreads();
  const float dx = v.x - mean, dy = v.y - mean, dz = v.z - mean, dw = v.w - mean;
  red[tid] = dx * dx + dy * dy + dz * dz + dw * dw;
  __syncthreads();
  for (int st = 128; st > 0; st >>= 1) {
    if (tid < st) red[tid] += red[tid + st];
    __syncthreads();
  }
  const float rstd = rsqrtf(red[0] * (1.f / HDIM) + 1e-6f);
  const int c = tid * 4;
  const float4 g4 = *(const float4*)(g + c);
  const float4 b4 = *(const float4*)(b + c);
  uint2 o;
  o.x = cvtpk(dx * rstd * g4.x + b4.x, dy * rstd * g4.y + b4.y);
  o.y = cvtpk(dz * rstd * g4.z + b4.z, dw * rstd * g4.w + b4.w);
  *(uint2*)(out + base + c) = o;
}

// ------------------------------------------------------------ expert groups
__launch_bounds__(256)
__global__ void build_groups(const int* __restrict__ pids, const int* __restrict__ mids,
                             int* __restrict__ gen_cnt, int* __restrict__ gen_list,
                             int* __restrict__ mod_cnt, int* __restrict__ mod_list) {
  const int t = blockIdx.x * 256 + threadIdx.x;
  if (t >= T_TOKENS) return;
  const int p = pids[t];
  const int ge = p & 7;
  int s = atomicAdd(&gen_cnt[ge], 1);
  if (s < 512) gen_list[ge * 512 + s] = t;
  const int g = mids[t] * 4 + (p & 3);
  s = atomicAdd(&mod_cnt[g], 1);
  if (s < 1024) mod_list[g * 1024 + s] = t;
}

// ------------------------------------------- weight transpose+convert: W[K][N] fp32 -> Wt[N][K] bf16
__launch_bounds__(256)
__global__ void convert_w(const float* __restrict__ W, unsigned short* __restrict__ Wt,
                          int K, int N) {
  const long zo = (long)blockIdx.z * K * N;
  const float* Wp = W + zo;
  unsigned short* Wo = Wt + zo;
  const int n0 = blockIdx.x * 64, k0 = blockIdx.y * 64;
  __shared__ float T[64][65];
  const int tid = threadIdx.x;
#pragma unroll
  for (int i = 0; i < 4; ++i) {
    const int item = tid + i * 256;
    const int kk = item >> 4, c4 = (item & 15) * 4;
    const float4 v = *(const float4*)(Wp + (long)(k0 + kk) * N + n0 + c4);
    T[c4 + 0][kk] = v.x; T[c4 + 1][kk] = v.y; T[c4 + 2][kk] = v.z; T[c4 + 3][kk] = v.w;
  }
  __syncthreads();
#pragma unroll
  for (int i = 0; i < 4; ++i) {
    const int item = tid + i * 256;
    const int nn = item >> 4, k4 = (item & 15) * 4;
    uint2 p;
    p.x = cvtpk(T[nn][k4 + 0], T[nn][k4 + 1]);
    p.y = cvtpk(T[nn][k4 + 2], T[nn][k4 + 3]);
    *(uint2*)(Wo + (long)(n0 + nn) * K + k0 + k4) = p;
  }
}

// --------------------------------------------------- bf16 MFMA tiled GEMM
// Double-buffered K-loop: stage(t+1) issued before compute(t), one barrier/step.
enum { MODE_DENSE = 0, MODE_GEN = 1, MODE_MOD = 2 };
enum { OM_F32R = 0, OM_BF16 = 1, OM_QKV = 2 };

template <int MODE, int OMODE, bool WBF16, bool BIAS>
__launch_bounds__(256)
__global__ void mgemm(const unsigned short* __restrict__ A,
                      const void* __restrict__ w0, const float* __restrict__ w1,
                      const float* __restrict__ w2, const float* __restrict__ w3,
                      long wstep, const float* __restrict__ bias,
                      const float* __restrict__ resid, void* __restrict__ Cout,
                      unsigned short* __restrict__ qb, unsigned short* __restrict__ kb,
                      unsigned short* __restrict__ vtb,
                      int K, int N,
                      const int* __restrict__ cnts, const int* __restrict__ rowlist,
                      int cap) {
  const int z = blockIdx.z;
  const int n0 = blockIdx.x * 128;
  const int m0 = blockIdx.y * 128;

  int Meff = 1 << 30;
  const int* list = nullptr;
  if constexpr (MODE != MODE_DENSE) {
    Meff = cnts[z];
    if (m0 >= Meff) return;
    list = rowlist + z * cap;
  }

  constexpr int BUFSZ = 128 * 64 * 2;  // 16 KB per buffer
  __shared__ char As[2 * BUFSZ];
  __shared__ char Bs[2 * BUFSZ];

  const int tid = threadIdx.x;
  const int w = tid >> 6;
  const int lane = tid & 63;
  const int wm = w >> 1, wn = w & 1;
  const int srow = lane >> 3, sc = lane & 7;

  const unsigned short* asrc[4];
#pragma unroll
  for (int i = 0; i < 4; ++i) {
    const int r = w * 32 + i * 8 + srow;
    long tok;
    if constexpr (MODE == MODE_DENSE) {
      tok = m0 + r;
    } else {
      int gm = m0 + r;
      if (gm >= Meff) gm = Meff - 1;
      tok = (long)list[gm];
    }
    asrc[i] = A + tok * (long)K + (sc ^ (r & 7)) * 8;
  }

  const unsigned short* bsrc[4];
  const float* bptr[4];
  int boff[4];
  if constexpr (WBF16) {
    const unsigned short* W = (const unsigned short*)w0;
    if constexpr (MODE != MODE_DENSE) W += (long)z * wstep;
#pragma unroll
    for (int i = 0; i < 4; ++i) {
      const int r = w * 32 + i * 8 + srow;
      bsrc[i] = W + (long)(n0 + r) * K + (sc ^ (r & 7)) * 8;
    }
  } else {
    const float* W;
    if constexpr (MODE == MODE_MOD) {
      const int mm = z >> 2;
      const float* basep = (mm == 0) ? (const float*)w0 : (mm == 1) ? w1 : (mm == 2) ? w2 : w3;
      W = basep + (long)(z & 3) * wstep;
    } else {
      W = (const float*)w0 + (MODE != MODE_DENSE ? (long)z * wstep : 0);
    }
#pragma unroll
    for (int j = 0; j < 4; ++j) {
      const int item = tid + j * 256;
      const int kc = item >> 7;
      const int nl = item & 127;
      bptr[j] = W + (long)(kc * 8) * N + n0 + nl;
      boff[j] = (nl * 128 + kc * 16) ^ ((nl & 7) << 4);
    }
  }

  f32x4 acc[4][4] = {};
  float kv[4][8];  // fp32-B staging registers (live across compute)

  auto stageA = [&](int s, int kt) {
#pragma unroll
    for (int i = 0; i < 4; ++i) gl16(asrc[i] + kt, As + s * BUFSZ + w * 4096 + i * 1024);
  };
  auto stageB16 = [&](int s, int kt) {
#pragma unroll
    for (int i = 0; i < 4; ++i) gl16(bsrc[i] + kt, Bs + s * BUFSZ + w * 4096 + i * 1024);
  };
  auto loadB = [&](int kt) {
#pragma unroll
    for (int j = 0; j < 4; ++j) {
      const float* bp = bptr[j] + (long)kt * N;
#pragma unroll
      for (int u = 0; u < 8; ++u) kv[j][u] = bp[(long)u * N];
    }
  };
  auto writeB = [&](int s) {
#pragma unroll
    for (int j = 0; j < 4; ++j) {
      uint4 p;
      p.x = cvtpk(kv[j][0], kv[j][1]);
      p.y = cvtpk(kv[j][2], kv[j][3]);
      p.z = cvtpk(kv[j][4], kv[j][5]);
      p.w = cvtpk(kv[j][6], kv[j][7]);
      *(uint4*)(Bs + s * BUFSZ + boff[j]) = p;
    }
  };
  auto compute = [&](int s) {
#pragma unroll
    for (int kk = 0; kk < 2; ++kk) {
      const int kb2 = kk * 64 + (lane >> 4) * 16;
      bf16x8 af[4], bfr[4];
#pragma unroll
      for (int f = 0; f < 4; ++f) {
        const int ar = wm * 64 + f * 16 + (lane & 15);
        af[f] = *(bf16x8*)(As + s * BUFSZ + ((ar * 128 + kb2) ^ ((ar & 7) << 4)));
        const int br = wn * 64 + f * 16 + (lane & 15);
        bfr[f] = *(bf16x8*)(Bs + s * BUFSZ + ((br * 128 + kb2) ^ ((br & 7) << 4)));
      }
#pragma unroll
      for (int mf = 0; mf < 4; ++mf)
#pragma unroll
        for (int nf = 0; nf < 4; ++nf)
          acc[mf][nf] =
              __builtin_amdgcn_mfma_f32_16x16x32_bf16(af[mf], bfr[nf], acc[mf][nf], 0, 0, 0);
    }
  };

  const int nk = K >> 6;
  stageA(0, 0);
  if constexpr (WBF16) {
    stageB16(0, 0);
  } else {
    loadB(0);
    writeB(0);
  }
  __syncthreads();

  int sel = 0;
  for (int t = 0; t < nk; ++t) {
    const bool more = (t + 1) < nk;
    const int ktn = (t + 1) * 64;
    if (more) {
      stageA(sel ^ 1, ktn);
      if constexpr (WBF16) stageB16(sel ^ 1, ktn);
      else loadB(ktn);
    }
    compute(sel);
    if constexpr (!WBF16) {
      if (more) writeB(sel ^ 1);
    }
    __syncthreads();
    sel ^= 1;
  }

  // ---- epilogue (C/D layout: col=lane&15, row=(lane>>4)*4+r)
  const int lr4 = (lane >> 4) * 4;
  const int lc = lane & 15;
#pragma unroll
  for (int mf = 0; mf < 4; ++mf) {
#pragma unroll
    for (int r = 0; r < 4; ++r) {
      const int gm = m0 + wm * 64 + mf * 16 + lr4 + r;
      long orow;
      if constexpr (MODE == MODE_DENSE) {
        orow = gm;
      } else {
        if (gm >= Meff) continue;
        orow = (long)list[gm];
      }
#pragma unroll
      for (int nf = 0; nf < 4; ++nf) {
        const int gc = n0 + wn * 64 + nf * 16 + lc;
        float val = acc[mf][nf][r];
        if constexpr (BIAS) val += bias[gc];
        if constexpr (OMODE == OM_F32R) {
          val += resid[orow * (long)N + gc];
          ((float*)Cout)[orow * (long)N + gc] = val;
        } else if constexpr (OMODE == OM_BF16) {
          ((unsigned short*)Cout)[orow * (long)N + gc] = f2bf(val);
        } else {  // OM_QKV: Q pre-scaled by 0.125*log2(e) for exp2 softmax
          const int bb = (int)(orow >> 11), tl = (int)orow & 2047;
          const int seg = gc >> 10, hc = gc & 1023, h = hc >> 6, d = hc & 63;
          if (seg == 0)
            qb[(((long)(bb * 16 + h) * 2048) + tl) * 64 + d] = f2bf(val * 0.18033688011112042f);
          else if (seg == 1)
            kb[(((long)(bb * 16 + h) * 2048) + tl) * 64 + d] = f2bf(val);
          else
            vtb[((long)(bb * 16 + h) * 64 + d) * 2048 + tl] = f2bf(val);
        }
      }
    }
  }
}

// ----------------------------------------------------------- MFMA attention
// Swapped QK^T (St = K·Q^T), KVBLK=128 single-buffered (per-tile softmax
// overhead amortized), XCD-aware head remap (K/V L2-resident), P rows at
// 272B stride (2-way write banks = free), defer-max. exp2-domain softmax.
__launch_bounds__(256)
__global__ void attn_kernel(const unsigned short* __restrict__ Qb,
                            const unsigned short* __restrict__ Kb,
                            const unsigned short* __restrict__ Vtb,
                            unsigned short* __restrict__ out) {
  // flat dispatch id -> xcd = id & 7; each XCD owns 4 heads, all 32 q-tiles
  const int lin = blockIdx.x + blockIdx.y * 32;   // 0..1023
  const int xcd = lin & 7, rank = lin >> 3;       // rank 0..127
  const int bh = xcd * 4 + (rank >> 5);
  const int qt = rank & 31;
  const int b = bh >> 4, h = bh & 15;
  const int tid = threadIdx.x;
  const int w = tid >> 6;
  const int lane = tid & 63;
  const int g = lane >> 4;   // 0..3
  const int q = lane & 15;   // this lane's q col (St) / d col (O)

  constexpr int PSTR = 272;            // P row stride: 256B data + 16B pad
  __shared__ char Ksb[128 * 128];      // K[128 kv][64 d], swizzled
  __shared__ char Vsb[64 * 256];       // Vt[64 d][128 kv], swizzled
  __shared__ char Psb[4 * 16 * PSTR];  // per-wave P[16 q][128 k]
  char* Pwb = Psb + w * 16 * PSTR;

  const unsigned short* Qh = Qb + ((long)(b * 16 + h) * 2048 + qt * 64) * 64;
  const unsigned short* Kh = Kb + (long)(b * 16 + h) * 2048 * 64;
  const unsigned short* Vh = Vtb + (long)(b * 16 + h) * 64 * 2048;

  // Q B-fragments for this wave's 16 q rows (col q, k-dim = d)
  bf16x8 qf[2];
#pragma unroll
  for (int kst = 0; kst < 2; ++kst)
    qf[kst] = *(const bf16x8*)(Qh + (w * 16 + q) * 64 + kst * 32 + g * 8);

  // staging pointers (swizzle pre-applied on global side)
  const unsigned short* ksrc[4];
  const unsigned short* vsrc[4];
  char* kld = Ksb + w * 4096;
  char* vld = Vsb + w * 4096;
#pragma unroll
  for (int i = 0; i < 4; ++i) {
    const int r = w * 32 + i * 8 + (lane >> 3);
    ksrc[i] = Kh + (long)r * 64 + ((lane & 7) ^ (r & 7)) * 8;
    const int d = w * 16 + i * 4 + (lane >> 4);
    vsrc[i] = Vh + (long)d * 2048 + ((lane & 15) ^ (d & 7)) * 8;
  }

  float m_run = -1e30f, l_run = 0.f;
  f32x4 acc[4] = {};

  for (int kt = 0; kt < 16; ++kt) {
    __syncthreads();
#pragma unroll
    for (int i = 0; i < 4; ++i) gl16(ksrc[i] + (long)kt * 128 * 64, kld + i * 1024);
#pragma unroll
    for (int i = 0; i < 4; ++i) gl16(vsrc[i] + kt * 128, vld + i * 1024);
    __syncthreads();

    // --- St = K·Q^T: sf[f] holds kv rows f*16+g*4+r, col q ---
    f32x4 sf[8];
#pragma unroll
    for (int f = 0; f < 8; ++f) {
      const int krow = f * 16 + q;
      const int sw = (krow & 7) << 4;
      const bf16x8 k0 = *(bf16x8*)(Ksb + krow * 128 + ((g * 16) ^ sw));
      const bf16x8 k1 = *(bf16x8*)(Ksb + krow * 128 + ((64 + g * 16) ^ sw));
      f32x4 t = {};
      t = __builtin_amdgcn_mfma_f32_16x16x32_bf16(k0, qf[0], t, 0, 0, 0);
      sf[f] = __builtin_amdgcn_mfma_f32_16x16x32_bf16(k1, qf[1], t, 0, 0, 0);
    }

    // --- online softmax (exp2 domain), per-q state, defer-max ---
    float pm = fmaxf(fmaxf(sf[0][0], sf[0][1]), fmaxf(sf[0][2], sf[0][3]));
#pragma unroll
    for (int f = 1; f < 8; ++f)
      pm = fmaxf(pm, fmaxf(fmaxf(sf[f][0], sf[f][1]), fmaxf(sf[f][2], sf[f][3])));
    pm = fmaxf(pm, __shfl_xor(pm, 16));
    pm = fmaxf(pm, __shfl_xor(pm, 32));
    float al = 1.f;
    if (!__all(pm - m_run <= 8.f)) {
      const float mn = fmaxf(m_run, pm);
      al = EXP2F(m_run - mn);
      m_run = mn;
#pragma unroll
      for (int r = 0; r < 4; ++r) {
        const float aO = __shfl(al, g * 4 + r, 64);
        acc[0][r] *= aO; acc[1][r] *= aO; acc[2][r] *= aO; acc[3][r] *= aO;
      }
    }

    float ls = 0.f;
#pragma unroll
    for (int f = 0; f < 8; ++f) {
#pragma unroll
      for (int r = 0; r < 4; ++r) sf[f][r] = EXP2F(sf[f][r] - m_run);
      ls += (sf[f][0] + sf[f][1]) + (sf[f][2] + sf[f][3]);
    }
    ls += __shfl_xor(ls, 16);
    ls += __shfl_xor(ls, 32);
    l_run = l_run * al + ls;

    // --- pack P pairs (consecutive k in-lane) -> per-wave LDS rows [q][k] ---
#pragma unroll
    for (int f = 0; f < 8; ++f) {
      const int base = q * PSTR + f * 32 + g * 8;
      *(unsigned*)(Pwb + base) = cvtpk(sf[f][0], sf[f][1]);
      *(unsigned*)(Pwb + base + 4) = cvtpk(sf[f][2], sf[f][3]);
    }

    // --- O += P·V  (A = P rows [q][k], B = Vt rows = V^T) ---
#pragma unroll
    for (int kst = 0; kst < 4; ++kst) {
      const bf16x8 pa = *(bf16x8*)(Pwb + q * PSTR + kst * 64 + g * 16);
#pragma unroll
      for (int df = 0; df < 4; ++df) {
        const int vrow = df * 16 + q;
        const int vsw = (vrow & 7) << 4;
        const bf16x8 vf = *(bf16x8*)(Vsb + vrow * 256 + ((kst * 64 + g * 16) ^ vsw));
        acc[df] = __builtin_amdgcn_mfma_f32_16x16x32_bf16(pa, vf, acc[df], 0, 0, 0);
      }
    }
  }

  float linv[4];
#pragma unroll
  for (int r = 0; r < 4; ++r) linv[r] = 1.f / __shfl(l_run, g * 4 + r, 64);
  unsigned short* op = out + (long)(b * 2048 + qt * 64 + w * 16) * 1024 + h * 64;
#pragma unroll
  for (int df = 0; df < 4; ++df)
#pragma unroll
    for (int r = 0; r < 4; ++r) {
      const int row = g * 4 + r;
      op[(long)row * 1024 + df * 16 + q] = f2bf(acc[df][r] * linv[r]);
    }
}

// ------------------------------------------------------------------- SiLU*up (bf16)
__launch_bounds__(256)
__global__ void silu_bf(const unsigned short* __restrict__ gu, unsigned short* __restrict__ inter,
                        int IE2, int IE, int shift) {
  const int total = T_TOKENS << shift;  // groups of 8
  for (int idx = blockIdx.x * 256 + threadIdx.x; idx < total; idx += gridDim.x * 256) {
    const int t = idx >> shift;
    const int r8 = (idx & ((1 << shift) - 1)) * 8;
    const unsigned short* gp = gu + (long)t * IE2 + r8;
    const uint4 gg = *(const uint4*)gp;
    const uint4 uu = *(const uint4*)(gp + IE);
    const unsigned gw[4] = {gg.x, gg.y, gg.z, gg.w};
    const unsigned uw[4] = {uu.x, uu.y, uu.z, uu.w};
    uint4 o;
    unsigned ow[4];
#pragma unroll
    for (int qq = 0; qq < 4; ++qq) {
      const float g0 = __uint_as_float(gw[qq] << 16);
      const float g1 = __uint_as_float(gw[qq] & 0xffff0000u);
      const float u0 = __uint_as_float(uw[qq] << 16);
      const float u1 = __uint_as_float(uw[qq] & 0xffff0000u);
      const float r0 = g0 / (1.f + __expf(-g0)) * u0;
      const float r1 = g1 / (1.f + __expf(-g1)) * u1;
      ow[qq] = cvtpk(r0, r1);
    }
    o.x = ow[0]; o.y = ow[1]; o.z = ow[2]; o.w = ow[3];
    *(uint4*)(inter + (long)t * IE + r8) = o;
  }
}

// ------------------------------------------------------------------- launch
extern "C" void kernel_launch(void* const* d_in, const int* in_sizes, int n_in,
                              void* d_out, int out_size, void* d_ws, size_t ws_size,
                              hipStream_t stream) {
  const float* x       = (const float*)d_in[0];
  const float* qkv_w   = (const float*)d_in[1];
  const float* qkv_b   = (const float*)d_in[2];
  const float* proj_w  = (const float*)d_in[3];
  const float* proj_b  = (const float*)d_in[4];
  const float* ln1_g   = (const float*)d_in[5];
  const float* ln1_b   = (const float*)d_in[6];
  const float* ln2_g   = (const float*)d_in[7];
  const float* ln2_b   = (const float*)d_in[8];
  const float* ln3_g   = (const float*)d_in[9];
  const float* ln3_b   = (const float*)d_in[10];
  const float* gen_gu  = (const float*)d_in[11];
  const float* gen_dn  = (const float*)d_in[12];
  const float* text_gu = (const float*)d_in[13];
  const float* text_dn = (const float*)d_in[14];
  const float* img_gu  = (const float*)d_in[15];
  const float* img_dn  = (const float*)d_in[16];
  const float* aud_gu  = (const float*)d_in[17];
  const float* aud_dn  = (const float*)d_in[18];
  const float* vid_gu  = (const float*)d_in[19];
  const float* vid_dn  = (const float*)d_in[20];
  const int* mids      = (const int*)d_in[21];
  const int* pids      = (const int*)d_in[22];
  float* out = (float*)d_out;
  char* ws = (char*)d_ws;

  const unsigned long MB = 1ul << 20;
  unsigned short* lnb   = (unsigned short*)(ws);            // 8 MB
  unsigned short* Qb    = (unsigned short*)(ws + 8 * MB);   // 8 MB
  unsigned short* Kb    = (unsigned short*)(ws + 16 * MB);  // 8 MB
  unsigned short* Vtb   = (unsigned short*)(ws + 24 * MB);  // 8 MB
  unsigned short* attno = (unsigned short*)(ws + 32 * MB);  // 8 MB
  unsigned short* wqkv  = (unsigned short*)(ws + 40 * MB);  // 6 MB
  unsigned short* wproj = (unsigned short*)(ws + 46 * MB);  // 2 MB
  unsigned short* wggu  = (unsigned short*)(ws + 48 * MB);  // 16 MB
  unsigned short* wgdn  = (unsigned short*)(ws + 64 * MB);  // 8 MB
  int* gen_cnt  = (int*)(ws + 72 * MB);
  int* mod_cnt  = gen_cnt + 8;
  int* gen_list = gen_cnt + 32;
  int* mod_list = gen_list + 8 * 512;
  unsigned short* guo    = Qb;   // 16 MB (Qb+Kb), reused after attention
  unsigned short* intero = Vtb;  // 8 MB, reused after attention

  (void)hipMemsetAsync(gen_cnt, 0, (8 + 16) * sizeof(int), stream);
  build_groups<<<16, 256, 0, stream>>>(pids, mids, gen_cnt, gen_list, mod_cnt, mod_list);

  convert_w<<<dim3(48, 16, 1), 256, 0, stream>>>(qkv_w, wqkv, 1024, 3072);
  convert_w<<<dim3(16, 16, 1), 256, 0, stream>>>(proj_w, wproj, 1024, 1024);
  convert_w<<<dim3(16, 16, 8), 256, 0, stream>>>(gen_gu, wggu, 1024, 1024);
  convert_w<<<dim3(16, 8, 8), 256, 0, stream>>>(gen_dn, wgdn, 512, 1024);

  // --- attention block ---
  ln_kernel<<<4096, 256, 0, stream>>>(x, ln1_g, ln1_b, lnb);
  mgemm<MODE_DENSE, OM_QKV, true, true><<<dim3(24, 32, 1), 256, 0, stream>>>(
      lnb, wqkv, nullptr, nullptr, nullptr, 0L, qkv_b, nullptr, nullptr,
      Qb, Kb, Vtb, 1024, 3072, nullptr, nullptr, 0);
  attn_kernel<<<dim3(32, 32, 1), 256, 0, stream>>>(Qb, Kb, Vtb, attno);
  mgemm<MODE_DENSE, OM_F32R, true, true><<<dim3(8, 32, 1), 256, 0, stream>>>(
      attno, wproj, nullptr, nullptr, nullptr, 0L, proj_b, x, out,
      nullptr, nullptr, nullptr, 1024, 1024, nullptr, nullptr, 0);

  // --- gen routed MLP (E=8, IE=512) ---
  ln_kernel<<<4096, 256, 0, stream>>>(out, ln2_g, ln2_b, lnb);
  mgemm<MODE_GEN, OM_BF16, true, false><<<dim3(8, 4, 8), 256, 0, stream>>>(
      lnb, wggu, nullptr, nullptr, nullptr, (long)1024 * 1024, nullptr, nullptr, guo,
      nullptr, nullptr, nullptr, 1024, 1024, gen_cnt, gen_list, 512);
  silu_bf<<<1024, 256, 0, stream>>>(guo, intero, 1024, 512, 6);
  mgemm<MODE_GEN, OM_F32R, true, false><<<dim3(8, 4, 8), 256, 0, stream>>>(
      intero, wgdn, nullptr, nullptr, nullptr, (long)1024 * 512, nullptr, out, out,
      nullptr, nullptr, nullptr, 512, 1024, gen_cnt, gen_list, 512);

  // --- modality routed MLP (4 tables, E=4, IE=1024), fp32-W staging path ---
  ln_kernel<<<4096, 256, 0, stream>>>(out, ln3_g, ln3_b, lnb);
  mgemm<MODE_MOD, OM_BF16, false, false><<<dim3(16, 8, 16), 256, 0, stream>>>(
      lnb, text_gu, img_gu, aud_gu, vid_gu, (long)1024 * 2048, nullptr, nullptr, guo,
      nullptr, nullptr, nullptr, 1024, 2048, mod_cnt, mod_list, 1024);
  silu_bf<<<2048, 256, 0, stream>>>(guo, intero, 2048, 1024, 7);
  mgemm<MODE_MOD, OM_F32R, false, false><<<dim3(8, 8, 16), 256, 0, stream>>>(
      intero, text_dn, img_dn, aud_dn, vid_dn, (long)1024 * 1024, nullptr, out, out,
      nullptr, nullptr, nullptr, 1024, 1024, mod_cnt, mod_list, 1024);
}